// Round 16
// baseline (164.172 us; speedup 1.0000x reference)
//
#include <hip/hip_runtime.h>
#include <cstdint>

typedef _Float16 f16;
typedef __attribute__((ext_vector_type(2))) __fp16 fp16v2;
typedef __attribute__((ext_vector_type(4))) _Float16 f16x4;
typedef __attribute__((ext_vector_type(8))) _Float16 f16x8;
typedef __attribute__((ext_vector_type(4))) float f32x4;
typedef __attribute__((ext_vector_type(16))) float f32x16;

#if __has_builtin(__builtin_amdgcn_exp2f)
#define EXP2F(x) __builtin_amdgcn_exp2f(x)
#else
#define EXP2F(x) exp2f(x)
#endif

#if __has_builtin(__builtin_amdgcn_fdot2)
#define FDOT2(a, b, c) __builtin_amdgcn_fdot2((a), (b), (c), false)
#else
#define FDOT2(a, b, c) ((c) + (float)(a)[0] * (float)(b)[0] + (float)(a)[1] * (float)(b)[1])
#endif

#define GLOAD_LDS16(gp, lp) \
  __builtin_amdgcn_global_load_lds((const __attribute__((address_space(1))) void*)(gp), \
                                   (__attribute__((address_space(3))) void*)(lp), 16, 0, 0)

// ---------------- fused f32->f16 convert + transposed cos/sin table ----------------
__global__ __launch_bounds__(256) void cvt_all(const float4* __restrict__ h, f16x4* __restrict__ h16,
                                               const float4* __restrict__ wq, f16x4* __restrict__ wq16,
                                               const float4* __restrict__ wo, f16x4* __restrict__ wo16,
                                               const float* __restrict__ cosb, const float* __restrict__ sinb,
                                               float2* __restrict__ cst) {
  int i = blockIdx.x * 256 + threadIdx.x;
  if (i >= 3145728) {
    const int i2 = i - 3145728;          // [0, 65536)
    const int d = i2 >> 11, l = i2 & 2047;
    cst[i2] = make_float2(cosb[l * 64 + d], sinb[l * 64 + d]);
    return;
  }
  const float4* src;
  f16x4* dst;
  if (i < 2097152) { src = h + i; dst = h16 + i; }
  else if (i < 2883584) { src = wq + (i - 2097152); dst = wq16 + (i - 2097152); }
  else { src = wo + (i - 2883584); dst = wo16 + (i - 2883584); }
  float4 v = *src;
  f16x4 o;
  o.x = (f16)v.x; o.y = (f16)v.y; o.z = (f16)v.z; o.w = (f16)v.w;
  *dst = o;
}

// ---------------- GEMM v2: 256x128 tile, BK=64, 2-slot counted-vmcnt pipeline (R11) --------
template<int EPI, int N, int K>
__global__ __launch_bounds__(512) void gemm_bt2(
    const f16* __restrict__ A, const f16* __restrict__ Bm,
    f16* __restrict__ Qf, f16* __restrict__ Kf, f16* __restrict__ Vf,
    float* __restrict__ Cout, const int* __restrict__ mask,
    const float2* __restrict__ cst) {
  constexpr int NT = N / 128;
  constexpr int NKT = K / 64;
  const int tid = threadIdx.x;
  const int lane = tid & 63;
  const int wid = tid >> 6;
  const int wm = wid >> 1;
  const int wn = wid & 1;

  constexpr int nwg = 32 * NT;
  constexpr int cpx = nwg >> 3;
  const int swz = (blockIdx.x & 7) * cpx + (blockIdx.x >> 3);
  const int bm = swz / NT;
  const int bn = swz % NT;

  __shared__ f16 sA[2][256 * 64];
  __shared__ f16 sB[2][128 * 64];

  const f16* Abase = A + (size_t)bm * 256 * K;
  const f16* Bbase = Bm + (size_t)bn * 128 * K;

  f32x4 acc[4][4] = {};
  f16x8 af[4][2], bf[4][2];

  const int rowt = tid >> 3;
  const int c8 = (tid & 7) ^ (rowt & 7);
  const bool swp = (EPI == 1) && (bn < 16);

#define STAGE_KT(SLOT, KT)                                                      \
  do {                                                                          \
    _Pragma("unroll")                                                           \
    for (int g = 0; g < 4; ++g)                                                 \
      GLOAD_LDS16(Abase + (size_t)(g * 64 + rowt) * K + (KT) * 64 + c8 * 8,     \
                  &sA[SLOT][g * 4096 + tid * 8]);                               \
    _Pragma("unroll")                                                           \
    for (int g = 0; g < 2; ++g)                                                 \
      GLOAD_LDS16(Bbase + (size_t)(g * 64 + rowt) * K + (KT) * 64 + c8 * 8,     \
                  &sB[SLOT][g * 4096 + tid * 8]);                               \
  } while (0)

#define MFMA_CLUSTER(KS)                                                        \
  do {                                                                          \
    __builtin_amdgcn_s_setprio(1);                                              \
    if (swp) {                                                                  \
      _Pragma("unroll")                                                         \
      for (int i = 0; i < 4; ++i)                                               \
        _Pragma("unroll")                                                       \
        for (int j = 0; j < 4; ++j)                                             \
          acc[i][j] = __builtin_amdgcn_mfma_f32_16x16x32_f16(bf[i][KS], af[j][KS], acc[i][j], 0, 0, 0); \
    } else {                                                                    \
      _Pragma("unroll")                                                         \
      for (int i = 0; i < 4; ++i)                                               \
        _Pragma("unroll")                                                       \
        for (int j = 0; j < 4; ++j)                                             \
          acc[i][j] = __builtin_amdgcn_mfma_f32_16x16x32_f16(af[i][KS], bf[j][KS], acc[i][j], 0, 0, 0); \
    }                                                                           \
    __builtin_amdgcn_s_setprio(0);                                              \
  } while (0)

#define KTILE(VMC, DOSTAGE, KT, SLOT)                                           \
  do {                                                                          \
    asm volatile("s_waitcnt vmcnt(" #VMC ")" ::: "memory");                     \
    __builtin_amdgcn_s_barrier();                                               \
    __builtin_amdgcn_sched_barrier(0);                                          \
    _Pragma("unroll")                                                           \
    for (int i = 0; i < 4; ++i) {                                               \
      _Pragma("unroll")                                                         \
      for (int ks = 0; ks < 2; ++ks) {                                          \
        af[i][ks] = *(const f16x8*)&sA[SLOT][(wm * 64 + i * 16 + (lane & 15)) * 64 + ((ks * 4 + (lane >> 4)) ^ (lane & 7)) * 8]; \
        bf[i][ks] = *(const f16x8*)&sB[SLOT][(wn * 64 + i * 16 + (lane & 15)) * 64 + ((ks * 4 + (lane >> 4)) ^ (lane & 7)) * 8]; \
      }                                                                         \
    }                                                                           \
    MFMA_CLUSTER(0);                                                            \
    asm volatile("s_waitcnt lgkmcnt(0)" ::: "memory");                          \
    __builtin_amdgcn_sched_barrier(0);                                          \
    __builtin_amdgcn_s_barrier();                                               \
    if (DOSTAGE) { STAGE_KT(SLOT, (KT) + 2); }                                  \
    __builtin_amdgcn_sched_barrier(0);                                          \
    MFMA_CLUSTER(1);                                                            \
  } while (0)

  STAGE_KT(0, 0);
  STAGE_KT(1, 1);
#pragma unroll 1
  for (int it = 0; it < NKT - 2; it += 2) {
    KTILE(6, true, it, 0);
    KTILE(6, true, it + 1, 1);
  }
  KTILE(6, false, NKT - 2, 0);
  KTILE(0, false, NKT - 1, 1);

  const int lo = lane & 15;
  if constexpr (EPI == 1) {
    const int head = bn * 2 + wn;
    if (head < 32) {
      f16* dst = (head < 16) ? Qf : Kf;
      const int h15 = head & 15;
      const int h16l = lane >> 4;
      const int ahi = h16l >> 1, kkl = h16l & 1;
      #pragma unroll
      for (int j = 0; j < 4; ++j) {
        const int grow = bm * 256 + wm * 64 + j * 16 + lo;
        const int bb = grow >> 11, ll = grow & 2047;
        float msc = 1.0f;
        if (head < 16) msc = mask[bb * 2048 + ll] ? 0.18033688011112042f : 0.0f;
        f16* base = dst + (size_t)(bb * 16 + h15) * 64 * 2048;
        union { f16x8 v; fp16v2 hh[4]; } u0, u1;
        #pragma unroll
        for (int i = 0; i < 2; ++i) {
          float y0[4], y1[4];
          #pragma unroll
          for (int r = 0; r < 4; ++r) {
            const float2 cs = cst[(size_t)(i * 16 + 4 * h16l + r) * 2048 + ll];
            const float xl = acc[i][j][r], xh = acc[i + 2][j][r];
            y0[r] = (xl * cs.x - xh * cs.y) * msc;
            y1[r] = (xh * cs.x + xl * cs.y) * msc;
          }
          u0.hh[i * 2 + 0] = __builtin_amdgcn_cvt_pkrtz(y0[0], y0[1]);
          u0.hh[i * 2 + 1] = __builtin_amdgcn_cvt_pkrtz(y0[2], y0[3]);
          u1.hh[i * 2 + 0] = __builtin_amdgcn_cvt_pkrtz(y1[0], y1[1]);
          u1.hh[i * 2 + 1] = __builtin_amdgcn_cvt_pkrtz(y1[2], y1[3]);
        }
        const int t = ll >> 5, q5 = ll & 31;
        f16* p = base + (size_t)t * 2048 + (ahi * 32 + q5) * 8;
        *(f16x8*)(p + (kkl + 0) * 512) = u0.v;
        *(f16x8*)(p + (kkl + 2) * 512) = u1.v;
      }
    } else {
      const int hv = head - 32;
      #pragma unroll
      for (int i = 0; i < 4; ++i) {
        #pragma unroll
        for (int j = 0; j < 4; ++j) {
          #pragma unroll
          for (int r = 0; r < 4; ++r) {
            const int gm = bm * 256 + wm * 64 + i * 16 + (lane >> 4) * 4 + r;
            const int bb = gm >> 11, ll = gm & 2047;
            const int dd = j * 16 + lo;
            const int k = ll & 31;
            const int i32 = (k & ~12) | ((k & 4) << 1) | ((k & 8) >> 1);  // swap bits 2,3
            const int cc = i32 >> 4, hih = (i32 >> 3) & 1, jj = i32 & 7;
            const int blk = dd >> 5, qq = dd & 31;
            Vf[((size_t)(bb * 16 + hv) * 64 + (ll >> 5)) * 2048 +
               (cc * 2 + blk) * 512 + hih * 256 + qq * 8 + jj] = (f16)acc[i][j][r];
          }
        }
      }
    }
  } else {
    #pragma unroll
    for (int i = 0; i < 4; ++i) {
      #pragma unroll
      for (int j = 0; j < 4; ++j) {
        #pragma unroll
        for (int r = 0; r < 4; ++r) {
          const int gm = bm * 256 + wm * 64 + i * 16 + (lane >> 4) * 4 + r;
          const int gn = bn * 128 + wn * 64 + j * 16 + lo;
          const float mv = mask[gm] ? 1.0f : 0.0f;
          Cout[(size_t)gm * 1024 + gn] = acc[i][j][r] * mv;
        }
      }
    }
  }
#undef KTILE
#undef MFMA_CLUSTER
#undef STAGE_KT
}

// ---------------- flash attention: LDS-deduped K/V, 64 q/wave, fixed-max, KV-split x2 ------
// grid: 512 blocks (64bh x 8qt) x 512 threads (8 waves = 4qw x 2kvh).
// K/V tiles staged into LDS ONCE per block (global_load_lds, 2-slot, counted vmcnt(2));
// all 4 qw waves ds_read the same tile -> L2 traffic /4 (was the binding pipe).
// Combine: kvh=1 stores f16-normalized o/l + l (verified R13); kvh=0 exact reconstruct.
#define QKBODY(SA, SB, kr)                                                       \
  do {                                                                           \
    __builtin_amdgcn_s_setprio(1);                                               \
    SA = __builtin_amdgcn_mfma_f32_32x32x16_f16(kr[0], qfa[0], z16, 0, 0, 0);    \
    SB = __builtin_amdgcn_mfma_f32_32x32x16_f16(kr[0], qfb[0], z16, 0, 0, 0);    \
    _Pragma("unroll")                                                            \
    for (int _k = 1; _k < 4; ++_k) {                                             \
      SA = __builtin_amdgcn_mfma_f32_32x32x16_f16(kr[_k], qfa[_k], SA, 0, 0, 0); \
      SB = __builtin_amdgcn_mfma_f32_32x32x16_f16(kr[_k], qfb[_k], SB, 0, 0, 0); \
    }                                                                            \
    __builtin_amdgcn_s_setprio(0);                                               \
  } while (0)

#define EXPPACK(SA, SB)                                                          \
  do {                                                                           \
    _Pragma("unroll")                                                            \
    for (int _i = 0; _i < 4; ++_i) {                                             \
      pa0.h[_i] = __builtin_amdgcn_cvt_pkrtz(EXP2F(SA[2 * _i]), EXP2F(SA[2 * _i + 1]));       \
      pa1.h[_i] = __builtin_amdgcn_cvt_pkrtz(EXP2F(SA[8 + 2 * _i]), EXP2F(SA[8 + 2 * _i + 1])); \
      la = FDOT2(pa0.h[_i], kOne, la);                                           \
      la = FDOT2(pa1.h[_i], kOne, la);                                           \
      pb0.h[_i] = __builtin_amdgcn_cvt_pkrtz(EXP2F(SB[2 * _i]), EXP2F(SB[2 * _i + 1]));       \
      pb1.h[_i] = __builtin_amdgcn_cvt_pkrtz(EXP2F(SB[8 + 2 * _i]), EXP2F(SB[8 + 2 * _i + 1])); \
      lb = FDOT2(pb0.h[_i], kOne, lb);                                           \
      lb = FDOT2(pb1.h[_i], kOne, lb);                                           \
    }                                                                            \
  } while (0)

#define PVBODY(vr)                                                               \
  do {                                                                           \
    __builtin_amdgcn_s_setprio(1);                                               \
    oa0 = __builtin_amdgcn_mfma_f32_32x32x16_f16(vr[0], pa0.v, oa0, 0, 0, 0);    \
    oa1 = __builtin_amdgcn_mfma_f32_32x32x16_f16(vr[1], pa0.v, oa1, 0, 0, 0);    \
    ob0 = __builtin_amdgcn_mfma_f32_32x32x16_f16(vr[0], pb0.v, ob0, 0, 0, 0);    \
    ob1 = __builtin_amdgcn_mfma_f32_32x32x16_f16(vr[1], pb0.v, ob1, 0, 0, 0);    \
    oa0 = __builtin_amdgcn_mfma_f32_32x32x16_f16(vr[2], pa1.v, oa0, 0, 0, 0);    \
    oa1 = __builtin_amdgcn_mfma_f32_32x32x16_f16(vr[3], pa1.v, oa1, 0, 0, 0);    \
    ob0 = __builtin_amdgcn_mfma_f32_32x32x16_f16(vr[2], pb1.v, ob0, 0, 0, 0);    \
    ob1 = __builtin_amdgcn_mfma_f32_32x32x16_f16(vr[3], pb1.v, ob1, 0, 0, 0);    \
    __builtin_amdgcn_s_setprio(0);                                               \
  } while (0)

// wave role: rgn = wid>>1 (0:K kvh0, 1:V kvh0, 2:K kvh1, 3:V kvh1), hh = wid&1 (2KB half)
#define ASTAGE(SLOT, T)                                                          \
  do {                                                                           \
    const f16* _s = sbase + (size_t)(T) * 2048;                                  \
    GLOAD_LDS16(_s,       &sKV[SLOT][srgn][shh * 1024]);                         \
    GLOAD_LDS16(_s + 512, &sKV[SLOT][srgn][shh * 1024 + 512]);                   \
  } while (0)

#define AKT(VMC, DOSTAGE, T, SLOT)                                               \
  do {                                                                           \
    asm volatile("s_waitcnt vmcnt(" #VMC ")" ::: "memory");                      \
    __builtin_amdgcn_s_barrier();                                                \
    __builtin_amdgcn_sched_barrier(0);                                           \
    f16x8 kf[4], vf[4];                                                          \
    _Pragma("unroll")                                                            \
    for (int _k = 0; _k < 4; ++_k)                                               \
      kf[_k] = *(const f16x8*)&sKV[SLOT][kvh * 2 + 0][_k * 512 + lane * 8];      \
    _Pragma("unroll")                                                            \
    for (int _c = 0; _c < 4; ++_c)                                               \
      vf[_c] = *(const f16x8*)&sKV[SLOT][kvh * 2 + 1][_c * 512 + lane * 8];      \
    QKBODY(sa, sb, kf);                                                          \
    EXPPACK(sa, sb);                                                             \
    asm volatile("s_waitcnt lgkmcnt(0)" ::: "memory");                           \
    __builtin_amdgcn_sched_barrier(0);                                           \
    __builtin_amdgcn_s_barrier();                                                \
    if (DOSTAGE) { ASTAGE(SLOT, (T) + 2); }                                      \
    __builtin_amdgcn_sched_barrier(0);                                           \
    PVBODY(vf);                                                                  \
  } while (0)

__global__ __launch_bounds__(512) void attn_kernel(const f16* __restrict__ Qf,
                                                   const f16* __restrict__ Kf,
                                                   const f16* __restrict__ Vf,
                                                   f16* __restrict__ Ow) {
  const int bid = (blockIdx.x & 7) * 64 + (blockIdx.x >> 3);  // XCD-chunked swizzle (512=8*64)
  const int bh = bid >> 3;
  const int qt = bid & 7;
  const int lane = threadIdx.x & 63;
  const int wid = threadIdx.x >> 6;
  const int qw = wid & 3;
  const int kvh = wid >> 2;
  const int hi = lane >> 5;
  const int q = lane & 31;

  __shared__ f16 sKV[2][4][2048];        // [slot][kvh*2 + K/V][2048 f16]  = 32 KB
  __shared__ f16 o16[4][2][32][68];      // f16-normalized partials        = 34.8 KB
  __shared__ float l_lds[4][2][32];      // 1 KB

  const f16* Qb = Qf + (size_t)bh * 64 * 2048;
  const f16* Kb = Kf + (size_t)bh * 64 * 2048;
  const f16* Vb = Vf + (size_t)bh * 64 * 2048;

  const int ta = qt * 8 + qw * 2;
  f16x8 qfa[4], qfb[4];
  {
    const f16* pa = Qb + (size_t)ta * 2048 + lane * 8;
    const f16* pb = pa + 2048;
    #pragma unroll
    for (int kk = 0; kk < 4; ++kk) {
      qfa[kk] = *(const f16x8*)&pa[kk * 512];
      qfb[kk] = *(const f16x8*)&pb[kk * 512];
    }
  }

  // staging role (all 8 waves participate; independent of qw/kvh compute roles)
  const int srgn = wid >> 1;            // 0..3 -> {K0, V0, K1, V1}
  const int shh = wid & 1;              // 2KB half
  const f16* sbase = ((srgn & 1) ? Vb : Kb) + (size_t)((srgn >> 1) * 32) * 2048 +
                     shh * 1024 + lane * 8;

  f32x16 oa0 = {}, oa1 = {}, ob0 = {}, ob1 = {};
  const f32x16 z16 = {};
  float la = 0.0f, lb = 0.0f;
  const fp16v2 kOne = {(__fp16)1.0f, (__fp16)1.0f};
  union PU { fp16v2 h[4]; f16x8 v; } pa0, pa1, pb0, pb1;
  f32x16 sa, sb;

  ASTAGE(0, 0);
  ASTAGE(1, 1);
#pragma unroll 1
  for (int t = 0; t < 28; t += 2) {
    AKT(2, true, t, 0);
    AKT(2, true, t + 1, 1);
  }
  AKT(2, true, 28, 0);    // stages tile 30
  AKT(2, true, 29, 1);    // stages tile 31
  AKT(2, false, 30, 0);
  AKT(0, false, 31, 1);

  float lha = la + __shfl_xor(la, 32, 64);
  float lhb = lb + __shfl_xor(lb, 32, 64);

  if (kvh == 1) {
    const float ia = 1.0f / lha, ib = 1.0f / lhb;
    #pragma unroll
    for (int blk = 0; blk < 2; ++blk)
      #pragma unroll
      for (int g = 0; g < 4; ++g) {
        f16x4 na, nb;
        #pragma unroll
        for (int j = 0; j < 4; ++j) {
          na[j] = (f16)((blk ? oa1[g * 4 + j] : oa0[g * 4 + j]) * ia);
          nb[j] = (f16)((blk ? ob1[g * 4 + j] : ob0[g * 4 + j]) * ib);
        }
        const int d = blk * 32 + g * 8 + 4 * hi;
        *(f16x4*)&o16[qw][0][q][d] = na;
        *(f16x4*)&o16[qw][1][q][d] = nb;
      }
    if (hi == 0) { l_lds[qw][0][q] = lha; l_lds[qw][1][q] = lhb; }
  }
  __syncthreads();
  if (kvh == 0) {
    const float l1a = l_lds[qw][0][q], l1b = l_lds[qw][1][q];
    const float inva = 1.0f / (lha + l1a);
    const float invb = 1.0f / (lhb + l1b);
    const float w1a = l1a * inva, w1b = l1b * invb;
    const int b = bh >> 4, h = bh & 15;
    const int qra = qt * 256 + qw * 64 + q;
    f16* orowa = Ow + ((size_t)(b * 2048 + qra)) * 1024 + h * 64;
    f16* orowb = orowa + 32 * 1024;
    #pragma unroll
    for (int blk = 0; blk < 2; ++blk) {
      #pragma unroll
      for (int g = 0; g < 4; ++g) {
        const int d = blk * 32 + g * 8 + 4 * hi;
        const f16x4 na = *(const f16x4*)&o16[qw][0][q][d];
        const f16x4 nb = *(const f16x4*)&o16[qw][1][q][d];
        f16x4 sta, stb;
        #pragma unroll
        for (int j = 0; j < 4; ++j) {
          sta[j] = (f16)((blk ? oa1[g * 4 + j] : oa0[g * 4 + j]) * inva + (float)na[j] * w1a);
          stb[j] = (f16)((blk ? ob1[g * 4 + j] : ob0[g * 4 + j]) * invb + (float)nb[j] * w1b);
        }
        *(f16x4*)&orowa[blk * 32 + g * 8 + 4 * hi] = sta;
        *(f16x4*)&orowb[blk * 32 + g * 8 + 4 * hi] = stb;
      }
    }
  }
}

// ---------------- launch ----------------
extern "C" void kernel_launch(void* const* d_in, const int* in_sizes, int n_in,
                              void* d_out, int out_size, void* d_ws, size_t ws_size,
                              hipStream_t stream) {
  const float* hidden = (const float*)d_in[0];
  const float* cosb   = (const float*)d_in[1];
  const float* sinb   = (const float*)d_in[2];
  const int*   mask   = (const int*)d_in[3];
  const float* wqkv   = (const float*)d_in[4];
  const float* wo     = (const float*)d_in[5];
  float* out = (float*)d_out;
  char* ws = (char*)d_ws;

  f16* h16    = (f16*)(ws + 0);           // 16 MB (reused as Ow after GEMM1)
  f16* wqkv16 = (f16*)(ws + 16777216);    // 6 MB
  f16* wo16   = (f16*)(ws + 23068672);    // 2 MB
  f16* Qfb    = (f16*)(ws + 25165824);    // 16 MB fragment blocks
  f16* Kfb    = (f16*)(ws + 41943040);    // 16 MB
  f16* Vfb    = (f16*)(ws + 58720256);    // 16 MB
  float2* cst = (float2*)(ws + 75497472); // 512 KB transposed cos/sin
  f16* Ow     = h16;

  cvt_all<<<12544, 256, 0, stream>>>((const float4*)hidden, (f16x4*)h16,
                                     (const float4*)wqkv, (f16x4*)wqkv16,
                                     (const float4*)wo, (f16x4*)wo16,
                                     cosb, sinb, cst);

  gemm_bt2<1, 3072, 1024><<<768, 512, 0, stream>>>(h16, wqkv16, Qfb, Kfb, Vfb,
                                                   nullptr, mask, cst);

  attn_kernel<<<512, 512, 0, stream>>>(Qfb, Kfb, Vfb, Ow);

  gemm_bt2<2, 1024, 1024><<<256, 512, 0, stream>>>(Ow, wo16, nullptr, nullptr, nullptr,
                                                   out, mask, nullptr);
}

// Round 17
// 162.638 us; speedup vs baseline: 1.0094x; 1.0094x over previous
//
#include <hip/hip_runtime.h>
#include <cstdint>

typedef _Float16 f16;
typedef __attribute__((ext_vector_type(2))) __fp16 fp16v2;
typedef __attribute__((ext_vector_type(4))) _Float16 f16x4;
typedef __attribute__((ext_vector_type(8))) _Float16 f16x8;
typedef __attribute__((ext_vector_type(4))) float f32x4;
typedef __attribute__((ext_vector_type(16))) float f32x16;

#if __has_builtin(__builtin_amdgcn_exp2f)
#define EXP2F(x) __builtin_amdgcn_exp2f(x)
#else
#define EXP2F(x) exp2f(x)
#endif

#if __has_builtin(__builtin_amdgcn_fdot2)
#define FDOT2(a, b, c) __builtin_amdgcn_fdot2((a), (b), (c), false)
#else
#define FDOT2(a, b, c) ((c) + (float)(a)[0] * (float)(b)[0] + (float)(a)[1] * (float)(b)[1])
#endif

#define GLOAD_LDS16(gp, lp) \
  __builtin_amdgcn_global_load_lds((const __attribute__((address_space(1))) void*)(gp), \
                                   (__attribute__((address_space(3))) void*)(lp), 16, 0, 0)

// ---------------- fused f32->f16 convert + transposed cos/sin table ----------------
__global__ __launch_bounds__(256) void cvt_all(const float4* __restrict__ h, f16x4* __restrict__ h16,
                                               const float4* __restrict__ wq, f16x4* __restrict__ wq16,
                                               const float4* __restrict__ wo, f16x4* __restrict__ wo16,
                                               const float* __restrict__ cosb, const float* __restrict__ sinb,
                                               float2* __restrict__ cst) {
  int i = blockIdx.x * 256 + threadIdx.x;
  if (i >= 3145728) {
    const int i2 = i - 3145728;          // [0, 65536)
    const int d = i2 >> 11, l = i2 & 2047;
    cst[i2] = make_float2(cosb[l * 64 + d], sinb[l * 64 + d]);
    return;
  }
  const float4* src;
  f16x4* dst;
  if (i < 2097152) { src = h + i; dst = h16 + i; }
  else if (i < 2883584) { src = wq + (i - 2097152); dst = wq16 + (i - 2097152); }
  else { src = wo + (i - 2883584); dst = wo16 + (i - 2883584); }
  float4 v = *src;
  f16x4 o;
  o.x = (f16)v.x; o.y = (f16)v.y; o.z = (f16)v.z; o.w = (f16)v.w;
  *dst = o;
}

// ---------------- GEMM v2: 256x128 tile, BK=64, 2-slot counted-vmcnt pipeline (R11) --------
template<int EPI, int N, int K>
__global__ __launch_bounds__(512) void gemm_bt2(
    const f16* __restrict__ A, const f16* __restrict__ Bm,
    f16* __restrict__ Qf, f16* __restrict__ Kf, f16* __restrict__ Vf,
    float* __restrict__ Cout, const int* __restrict__ mask,
    const float2* __restrict__ cst) {
  constexpr int NT = N / 128;
  constexpr int NKT = K / 64;
  const int tid = threadIdx.x;
  const int lane = tid & 63;
  const int wid = tid >> 6;
  const int wm = wid >> 1;
  const int wn = wid & 1;

  constexpr int nwg = 32 * NT;
  constexpr int cpx = nwg >> 3;
  const int swz = (blockIdx.x & 7) * cpx + (blockIdx.x >> 3);
  const int bm = swz / NT;
  const int bn = swz % NT;

  __shared__ f16 sA[2][256 * 64];
  __shared__ f16 sB[2][128 * 64];

  const f16* Abase = A + (size_t)bm * 256 * K;
  const f16* Bbase = Bm + (size_t)bn * 128 * K;

  f32x4 acc[4][4] = {};
  f16x8 af[4][2], bf[4][2];

  const int rowt = tid >> 3;
  const int c8 = (tid & 7) ^ (rowt & 7);
  const bool swp = (EPI == 1) && (bn < 16);

#define STAGE_KT(SLOT, KT)                                                      \
  do {                                                                          \
    _Pragma("unroll")                                                           \
    for (int g = 0; g < 4; ++g)                                                 \
      GLOAD_LDS16(Abase + (size_t)(g * 64 + rowt) * K + (KT) * 64 + c8 * 8,     \
                  &sA[SLOT][g * 4096 + tid * 8]);                               \
    _Pragma("unroll")                                                           \
    for (int g = 0; g < 2; ++g)                                                 \
      GLOAD_LDS16(Bbase + (size_t)(g * 64 + rowt) * K + (KT) * 64 + c8 * 8,     \
                  &sB[SLOT][g * 4096 + tid * 8]);                               \
  } while (0)

#define MFMA_CLUSTER(KS)                                                        \
  do {                                                                          \
    __builtin_amdgcn_s_setprio(1);                                              \
    if (swp) {                                                                  \
      _Pragma("unroll")                                                         \
      for (int i = 0; i < 4; ++i)                                               \
        _Pragma("unroll")                                                       \
        for (int j = 0; j < 4; ++j)                                             \
          acc[i][j] = __builtin_amdgcn_mfma_f32_16x16x32_f16(bf[i][KS], af[j][KS], acc[i][j], 0, 0, 0); \
    } else {                                                                    \
      _Pragma("unroll")                                                         \
      for (int i = 0; i < 4; ++i)                                               \
        _Pragma("unroll")                                                       \
        for (int j = 0; j < 4; ++j)                                             \
          acc[i][j] = __builtin_amdgcn_mfma_f32_16x16x32_f16(af[i][KS], bf[j][KS], acc[i][j], 0, 0, 0); \
    }                                                                           \
    __builtin_amdgcn_s_setprio(0);                                              \
  } while (0)

#define KTILE(VMC, DOSTAGE, KT, SLOT)                                           \
  do {                                                                          \
    asm volatile("s_waitcnt vmcnt(" #VMC ")" ::: "memory");                     \
    __builtin_amdgcn_s_barrier();                                               \
    __builtin_amdgcn_sched_barrier(0);                                          \
    _Pragma("unroll")                                                           \
    for (int i = 0; i < 4; ++i) {                                               \
      _Pragma("unroll")                                                         \
      for (int ks = 0; ks < 2; ++ks) {                                          \
        af[i][ks] = *(const f16x8*)&sA[SLOT][(wm * 64 + i * 16 + (lane & 15)) * 64 + ((ks * 4 + (lane >> 4)) ^ (lane & 7)) * 8]; \
        bf[i][ks] = *(const f16x8*)&sB[SLOT][(wn * 64 + i * 16 + (lane & 15)) * 64 + ((ks * 4 + (lane >> 4)) ^ (lane & 7)) * 8]; \
      }                                                                         \
    }                                                                           \
    MFMA_CLUSTER(0);                                                            \
    asm volatile("s_waitcnt lgkmcnt(0)" ::: "memory");                          \
    __builtin_amdgcn_sched_barrier(0);                                          \
    __builtin_amdgcn_s_barrier();                                               \
    if (DOSTAGE) { STAGE_KT(SLOT, (KT) + 2); }                                  \
    __builtin_amdgcn_sched_barrier(0);                                          \
    MFMA_CLUSTER(1);                                                            \
  } while (0)

  STAGE_KT(0, 0);
  STAGE_KT(1, 1);
#pragma unroll 1
  for (int it = 0; it < NKT - 2; it += 2) {
    KTILE(6, true, it, 0);
    KTILE(6, true, it + 1, 1);
  }
  KTILE(6, false, NKT - 2, 0);
  KTILE(0, false, NKT - 1, 1);

  const int lo = lane & 15;
  if constexpr (EPI == 1) {
    const int head = bn * 2 + wn;
    if (head < 32) {
      f16* dst = (head < 16) ? Qf : Kf;
      const int h15 = head & 15;
      const int h16l = lane >> 4;
      const int ahi = h16l >> 1, kkl = h16l & 1;
      #pragma unroll
      for (int j = 0; j < 4; ++j) {
        const int grow = bm * 256 + wm * 64 + j * 16 + lo;
        const int bb = grow >> 11, ll = grow & 2047;
        float msc = 1.0f;
        if (head < 16) msc = mask[bb * 2048 + ll] ? 0.18033688011112042f : 0.0f;
        f16* base = dst + (size_t)(bb * 16 + h15) * 64 * 2048;
        union { f16x8 v; fp16v2 hh[4]; } u0, u1;
        #pragma unroll
        for (int i = 0; i < 2; ++i) {
          float y0[4], y1[4];
          #pragma unroll
          for (int r = 0; r < 4; ++r) {
            const float2 cs = cst[(size_t)(i * 16 + 4 * h16l + r) * 2048 + ll];
            const float xl = acc[i][j][r], xh = acc[i + 2][j][r];
            y0[r] = (xl * cs.x - xh * cs.y) * msc;
            y1[r] = (xh * cs.x + xl * cs.y) * msc;
          }
          u0.hh[i * 2 + 0] = __builtin_amdgcn_cvt_pkrtz(y0[0], y0[1]);
          u0.hh[i * 2 + 1] = __builtin_amdgcn_cvt_pkrtz(y0[2], y0[3]);
          u1.hh[i * 2 + 0] = __builtin_amdgcn_cvt_pkrtz(y1[0], y1[1]);
          u1.hh[i * 2 + 1] = __builtin_amdgcn_cvt_pkrtz(y1[2], y1[3]);
        }
        const int t = ll >> 5, q5 = ll & 31;
        f16* p = base + (size_t)t * 2048 + (ahi * 32 + q5) * 8;
        *(f16x8*)(p + (kkl + 0) * 512) = u0.v;
        *(f16x8*)(p + (kkl + 2) * 512) = u1.v;
      }
    } else {
      const int hv = head - 32;
      #pragma unroll
      for (int i = 0; i < 4; ++i) {
        #pragma unroll
        for (int j = 0; j < 4; ++j) {
          #pragma unroll
          for (int r = 0; r < 4; ++r) {
            const int gm = bm * 256 + wm * 64 + i * 16 + (lane >> 4) * 4 + r;
            const int bb = gm >> 11, ll = gm & 2047;
            const int dd = j * 16 + lo;
            const int k = ll & 31;
            const int i32 = (k & ~12) | ((k & 4) << 1) | ((k & 8) >> 1);  // swap bits 2,3
            const int cc = i32 >> 4, hih = (i32 >> 3) & 1, jj = i32 & 7;
            const int blk = dd >> 5, qq = dd & 31;
            Vf[((size_t)(bb * 16 + hv) * 64 + (ll >> 5)) * 2048 +
               (cc * 2 + blk) * 512 + hih * 256 + qq * 8 + jj] = (f16)acc[i][j][r];
          }
        }
      }
    }
  } else {
    #pragma unroll
    for (int i = 0; i < 4; ++i) {
      #pragma unroll
      for (int j = 0; j < 4; ++j) {
        #pragma unroll
        for (int r = 0; r < 4; ++r) {
          const int gm = bm * 256 + wm * 64 + i * 16 + (lane >> 4) * 4 + r;
          const int gn = bn * 128 + wn * 64 + j * 16 + lo;
          const float mv = mask[gm] ? 1.0f : 0.0f;
          Cout[(size_t)gm * 1024 + gn] = acc[i][j][r] * mv;
        }
      }
    }
  }
#undef KTILE
#undef MFMA_CLUSTER
#undef STAGE_KT
}

// ---------------- flash attention: 64 q/wave (2 groups), fixed-max, KV-split x2 (R11) ------
// Single change vs R11: __launch_bounds__(512, 2) gives the register allocator headroom
// (LDS caps residency at 4 waves/SIMD regardless; VGPR up to ~512 is free) so the 2-deep
// K/V prefetch stays LIVE in registers instead of being demoted to just-in-time loads.
#define LOADKV(kd, vd, kp, vp)                       \
  do {                                               \
    _Pragma("unroll")                                \
    for (int _i = 0; _i < 4; ++_i) {                 \
      kd[_i] = *(const f16x8*)&(kp)[_i * 512];       \
      vd[_i] = *(const f16x8*)&(vp)[_i * 512];       \
    }                                                \
  } while (0)

#define ATTN_BODY64(kr, vr)                                                      \
  do {                                                                           \
    f32x16 sa = {}, sb = {};                                                     \
    __builtin_amdgcn_s_setprio(1);                                               \
    _Pragma("unroll")                                                            \
    for (int _k = 0; _k < 4; ++_k)                                               \
      sa = __builtin_amdgcn_mfma_f32_32x32x16_f16(kr[_k], qfa[_k], sa, 0, 0, 0); \
    _Pragma("unroll")                                                            \
    for (int _k = 0; _k < 4; ++_k)                                               \
      sb = __builtin_amdgcn_mfma_f32_32x32x16_f16(kr[_k], qfb[_k], sb, 0, 0, 0); \
    __builtin_amdgcn_s_setprio(0);                                               \
    union PU { fp16v2 h[4]; f16x8 v; } pa0, pa1, pb0, pb1;                       \
    _Pragma("unroll")                                                            \
    for (int _i = 0; _i < 4; ++_i) {                                             \
      pa0.h[_i] = __builtin_amdgcn_cvt_pkrtz(EXP2F(sa[2 * _i]), EXP2F(sa[2 * _i + 1]));       \
      pa1.h[_i] = __builtin_amdgcn_cvt_pkrtz(EXP2F(sa[8 + 2 * _i]), EXP2F(sa[8 + 2 * _i + 1])); \
      la = FDOT2(pa0.h[_i], kOne, la);                                           \
      la = FDOT2(pa1.h[_i], kOne, la);                                           \
    }                                                                            \
    _Pragma("unroll")                                                            \
    for (int _i = 0; _i < 4; ++_i) {                                             \
      pb0.h[_i] = __builtin_amdgcn_cvt_pkrtz(EXP2F(sb[2 * _i]), EXP2F(sb[2 * _i + 1]));       \
      pb1.h[_i] = __builtin_amdgcn_cvt_pkrtz(EXP2F(sb[8 + 2 * _i]), EXP2F(sb[8 + 2 * _i + 1])); \
      lb = FDOT2(pb0.h[_i], kOne, lb);                                           \
      lb = FDOT2(pb1.h[_i], kOne, lb);                                           \
    }                                                                            \
    __builtin_amdgcn_s_setprio(1);                                               \
    oa0 = __builtin_amdgcn_mfma_f32_32x32x16_f16(vr[0], pa0.v, oa0, 0, 0, 0);    \
    oa1 = __builtin_amdgcn_mfma_f32_32x32x16_f16(vr[1], pa0.v, oa1, 0, 0, 0);    \
    ob0 = __builtin_amdgcn_mfma_f32_32x32x16_f16(vr[0], pb0.v, ob0, 0, 0, 0);    \
    ob1 = __builtin_amdgcn_mfma_f32_32x32x16_f16(vr[1], pb0.v, ob1, 0, 0, 0);    \
    oa0 = __builtin_amdgcn_mfma_f32_32x32x16_f16(vr[2], pa1.v, oa0, 0, 0, 0);    \
    oa1 = __builtin_amdgcn_mfma_f32_32x32x16_f16(vr[3], pa1.v, oa1, 0, 0, 0);    \
    ob0 = __builtin_amdgcn_mfma_f32_32x32x16_f16(vr[2], pb1.v, ob0, 0, 0, 0);    \
    ob1 = __builtin_amdgcn_mfma_f32_32x32x16_f16(vr[3], pb1.v, ob1, 0, 0, 0);    \
    __builtin_amdgcn_s_setprio(0);                                               \
  } while (0)

__global__ __launch_bounds__(512, 2) void attn_kernel(const f16* __restrict__ Qf,
                                                      const f16* __restrict__ Kf,
                                                      const f16* __restrict__ Vf,
                                                      f16* __restrict__ Ow) {
  const int bid = (blockIdx.x & 7) * 64 + (blockIdx.x >> 3);  // XCD-chunked swizzle (512=8*64)
  const int bh = bid >> 3;
  const int qt = bid & 7;
  const int lane = threadIdx.x & 63;
  const int wid = threadIdx.x >> 6;
  const int qw = wid & 3;
  const int kvh = wid >> 2;
  const int hi = lane >> 5;
  const int q = lane & 31;

  __shared__ float o_lds[8][32][65];
  __shared__ float l_lds[8][32];

  const f16* Qb = Qf + (size_t)bh * 64 * 2048;
  const f16* Kb = Kf + (size_t)bh * 64 * 2048;
  const f16* Vb = Vf + (size_t)bh * 64 * 2048;

  const int ta = qt * 8 + qw * 2;
  f16x8 qfa[4], qfb[4];
  {
    const f16* pa = Qb + (size_t)ta * 2048 + lane * 8;
    const f16* pb = pa + 2048;
    #pragma unroll
    for (int kk = 0; kk < 4; ++kk) {
      qfa[kk] = *(const f16x8*)&pa[kk * 512];
      qfb[kk] = *(const f16x8*)&pb[kk * 512];
    }
  }

  f32x16 oa0 = {}, oa1 = {}, ob0 = {}, ob1 = {};
  float la = 0.0f, lb = 0.0f;
  const fp16v2 kOne = {(__fp16)1.0f, (__fp16)1.0f};

  const f16* kptr = Kb + (size_t)(kvh * 32) * 2048 + lane * 8;
  const f16* vptr = Vb + (size_t)(kvh * 32) * 2048 + lane * 8;
  f16x8 ka[4], va[4], kn[4], vn[4];
  LOADKV(ka, va, kptr, vptr);
  for (int t = 0; t < 32; t += 2) {
    LOADKV(kn, vn, kptr + 2048, vptr + 2048);
    ATTN_BODY64(ka, va);
    if (t + 2 < 32)
      LOADKV(ka, va, kptr + 4096, vptr + 4096);
    ATTN_BODY64(kn, vn);
    kptr += 4096; vptr += 4096;
  }

  float lha = la + __shfl_xor(la, 32, 64);
  float lhb = lb + __shfl_xor(lb, 32, 64);

  if (kvh == 1) {
    #pragma unroll
    for (int blk = 0; blk < 2; ++blk)
      #pragma unroll
      for (int g = 0; g < 4; ++g)
        #pragma unroll
        for (int j = 0; j < 4; ++j) {
          const int d = blk * 32 + g * 8 + 4 * hi + j;
          o_lds[qw * 2 + 0][q][d] = blk ? oa1[g * 4 + j] : oa0[g * 4 + j];
          o_lds[qw * 2 + 1][q][d] = blk ? ob1[g * 4 + j] : ob0[g * 4 + j];
        }
    if (hi == 0) { l_lds[qw * 2 + 0][q] = lha; l_lds[qw * 2 + 1][q] = lhb; }
  }
  __syncthreads();
  if (kvh == 0) {
    const float inva = 1.0f / (lha + l_lds[qw * 2 + 0][q]);
    const float invb = 1.0f / (lhb + l_lds[qw * 2 + 1][q]);
    const int b = bh >> 4, h = bh & 15;
    const int qra = qt * 256 + qw * 64 + q;
    f16* orowa = Ow + ((size_t)(b * 2048 + qra)) * 1024 + h * 64;
    f16* orowb = orowa + 32 * 1024;
    #pragma unroll
    for (int blk = 0; blk < 2; ++blk) {
      #pragma unroll
      for (int g = 0; g < 4; ++g) {
        f16x4 sta, stb;
        #pragma unroll
        for (int j = 0; j < 4; ++j) {
          const int d = blk * 32 + g * 8 + 4 * hi + j;
          sta[j] = (f16)(((blk ? oa1[g * 4 + j] : oa0[g * 4 + j]) + o_lds[qw * 2 + 0][q][d]) * inva);
          stb[j] = (f16)(((blk ? ob1[g * 4 + j] : ob0[g * 4 + j]) + o_lds[qw * 2 + 1][q][d]) * invb);
        }
        *(f16x4*)&orowa[blk * 32 + g * 8 + 4 * hi] = sta;
        *(f16x4*)&orowb[blk * 32 + g * 8 + 4 * hi] = stb;
      }
    }
  }
}

// ---------------- launch ----------------
extern "C" void kernel_launch(void* const* d_in, const int* in_sizes, int n_in,
                              void* d_out, int out_size, void* d_ws, size_t ws_size,
                              hipStream_t stream) {
  const float* hidden = (const float*)d_in[0];
  const float* cosb   = (const float*)d_in[1];
  const float* sinb   = (const float*)d_in[2];
  const int*   mask   = (const int*)d_in[3];
  const float* wqkv   = (const float*)d_in[4];
  const float* wo     = (const float*)d_in[5];
  float* out = (float*)d_out;
  char* ws = (char*)d_ws;

  f16* h16    = (f16*)(ws + 0);           // 16 MB (reused as Ow after GEMM1)
  f16* wqkv16 = (f16*)(ws + 16777216);    // 6 MB
  f16* wo16   = (f16*)(ws + 23068672);    // 2 MB
  f16* Qfb    = (f16*)(ws + 25165824);    // 16 MB fragment blocks
  f16* Kfb    = (f16*)(ws + 41943040);    // 16 MB
  f16* Vfb    = (f16*)(ws + 58720256);    // 16 MB
  float2* cst = (float2*)(ws + 75497472); // 512 KB transposed cos/sin
  f16* Ow     = h16;

  cvt_all<<<12544, 256, 0, stream>>>((const float4*)hidden, (f16x4*)h16,
                                     (const float4*)wqkv, (f16x4*)wqkv16,
                                     (const float4*)wo, (f16x4*)wo16,
                                     cosb, sinb, cst);

  gemm_bt2<1, 3072, 1024><<<768, 512, 0, stream>>>(h16, wqkv16, Qfb, Kfb, Vfb,
                                                   nullptr, mask, cst);

  attn_kernel<<<512, 512, 0, stream>>>(Qfb, Kfb, Vfb, Ow);

  gemm_bt2<2, 1024, 1024><<<256, 512, 0, stream>>>(Ow, wo16, nullptr, nullptr, nullptr,
                                                   out, mask, nullptr);
}

// Round 18
// 162.537 us; speedup vs baseline: 1.0101x; 1.0006x over previous
//
#include <hip/hip_runtime.h>
#include <cstdint>

typedef _Float16 f16;
typedef __attribute__((ext_vector_type(2))) __fp16 fp16v2;
typedef __attribute__((ext_vector_type(4))) _Float16 f16x4;
typedef __attribute__((ext_vector_type(8))) _Float16 f16x8;
typedef __attribute__((ext_vector_type(4))) float f32x4;
typedef __attribute__((ext_vector_type(16))) float f32x16;

#if __has_builtin(__builtin_amdgcn_exp2f)
#define EXP2F(x) __builtin_amdgcn_exp2f(x)
#else
#define EXP2F(x) exp2f(x)
#endif

#if __has_builtin(__builtin_amdgcn_fdot2)
#define FDOT2(a, b, c) __builtin_amdgcn_fdot2((a), (b), (c), false)
#else
#define FDOT2(a, b, c) ((c) + (float)(a)[0] * (float)(b)[0] + (float)(a)[1] * (float)(b)[1])
#endif

#define GLOAD_LDS16(gp, lp) \
  __builtin_amdgcn_global_load_lds((const __attribute__((address_space(1))) void*)(gp), \
                                   (__attribute__((address_space(3))) void*)(lp), 16, 0, 0)

// ---------------- fused f32->f16 convert + transposed cos/sin table ----------------
__global__ __launch_bounds__(256) void cvt_all(const float4* __restrict__ h, f16x4* __restrict__ h16,
                                               const float4* __restrict__ wq, f16x4* __restrict__ wq16,
                                               const float4* __restrict__ wo, f16x4* __restrict__ wo16,
                                               const float* __restrict__ cosb, const float* __restrict__ sinb,
                                               float2* __restrict__ cst) {
  int i = blockIdx.x * 256 + threadIdx.x;
  if (i >= 3145728) {
    const int i2 = i - 3145728;          // [0, 65536)
    const int d = i2 >> 11, l = i2 & 2047;
    cst[i2] = make_float2(cosb[l * 64 + d], sinb[l * 64 + d]);
    return;
  }
  const float4* src;
  f16x4* dst;
  if (i < 2097152) { src = h + i; dst = h16 + i; }
  else if (i < 2883584) { src = wq + (i - 2097152); dst = wq16 + (i - 2097152); }
  else { src = wo + (i - 2883584); dst = wo16 + (i - 2883584); }
  float4 v = *src;
  f16x4 o;
  o.x = (f16)v.x; o.y = (f16)v.y; o.z = (f16)v.z; o.w = (f16)v.w;
  *dst = o;
}

// ---------------- GEMM v2: 256x128 tile, BK=64, 2-slot counted-vmcnt pipeline (R11) --------
template<int EPI, int N, int K>
__global__ __launch_bounds__(512) void gemm_bt2(
    const f16* __restrict__ A, const f16* __restrict__ Bm,
    f16* __restrict__ Qf, f16* __restrict__ Kf, f16* __restrict__ Vf,
    float* __restrict__ Cout, const int* __restrict__ mask,
    const float2* __restrict__ cst) {
  constexpr int NT = N / 128;
  constexpr int NKT = K / 64;
  const int tid = threadIdx.x;
  const int lane = tid & 63;
  const int wid = tid >> 6;
  const int wm = wid >> 1;
  const int wn = wid & 1;

  constexpr int nwg = 32 * NT;
  constexpr int cpx = nwg >> 3;
  const int swz = (blockIdx.x & 7) * cpx + (blockIdx.x >> 3);
  const int bm = swz / NT;
  const int bn = swz % NT;

  __shared__ f16 sA[2][256 * 64];
  __shared__ f16 sB[2][128 * 64];

  const f16* Abase = A + (size_t)bm * 256 * K;
  const f16* Bbase = Bm + (size_t)bn * 128 * K;

  f32x4 acc[4][4] = {};
  f16x8 af[4][2], bf[4][2];

  const int rowt = tid >> 3;
  const int c8 = (tid & 7) ^ (rowt & 7);
  const bool swp = (EPI == 1) && (bn < 16);

#define STAGE_KT(SLOT, KT)                                                      \
  do {                                                                          \
    _Pragma("unroll")                                                           \
    for (int g = 0; g < 4; ++g)                                                 \
      GLOAD_LDS16(Abase + (size_t)(g * 64 + rowt) * K + (KT) * 64 + c8 * 8,     \
                  &sA[SLOT][g * 4096 + tid * 8]);                               \
    _Pragma("unroll")                                                           \
    for (int g = 0; g < 2; ++g)                                                 \
      GLOAD_LDS16(Bbase + (size_t)(g * 64 + rowt) * K + (KT) * 64 + c8 * 8,     \
                  &sB[SLOT][g * 4096 + tid * 8]);                               \
  } while (0)

#define MFMA_CLUSTER(KS)                                                        \
  do {                                                                          \
    __builtin_amdgcn_s_setprio(1);                                              \
    if (swp) {                                                                  \
      _Pragma("unroll")                                                         \
      for (int i = 0; i < 4; ++i)                                               \
        _Pragma("unroll")                                                       \
        for (int j = 0; j < 4; ++j)                                             \
          acc[i][j] = __builtin_amdgcn_mfma_f32_16x16x32_f16(bf[i][KS], af[j][KS], acc[i][j], 0, 0, 0); \
    } else {                                                                    \
      _Pragma("unroll")                                                         \
      for (int i = 0; i < 4; ++i)                                               \
        _Pragma("unroll")                                                       \
        for (int j = 0; j < 4; ++j)                                             \
          acc[i][j] = __builtin_amdgcn_mfma_f32_16x16x32_f16(af[i][KS], bf[j][KS], acc[i][j], 0, 0, 0); \
    }                                                                           \
    __builtin_amdgcn_s_setprio(0);                                              \
  } while (0)

#define KTILE(VMC, DOSTAGE, KT, SLOT)                                           \
  do {                                                                          \
    asm volatile("s_waitcnt vmcnt(" #VMC ")" ::: "memory");                     \
    __builtin_amdgcn_s_barrier();                                               \
    __builtin_amdgcn_sched_barrier(0);                                          \
    _Pragma("unroll")                                                           \
    for (int i = 0; i < 4; ++i) {                                               \
      _Pragma("unroll")                                                         \
      for (int ks = 0; ks < 2; ++ks) {                                          \
        af[i][ks] = *(const f16x8*)&sA[SLOT][(wm * 64 + i * 16 + (lane & 15)) * 64 + ((ks * 4 + (lane >> 4)) ^ (lane & 7)) * 8]; \
        bf[i][ks] = *(const f16x8*)&sB[SLOT][(wn * 64 + i * 16 + (lane & 15)) * 64 + ((ks * 4 + (lane >> 4)) ^ (lane & 7)) * 8]; \
      }                                                                         \
    }                                                                           \
    MFMA_CLUSTER(0);                                                            \
    asm volatile("s_waitcnt lgkmcnt(0)" ::: "memory");                          \
    __builtin_amdgcn_sched_barrier(0);                                          \
    __builtin_amdgcn_s_barrier();                                               \
    if (DOSTAGE) { STAGE_KT(SLOT, (KT) + 2); }                                  \
    __builtin_amdgcn_sched_barrier(0);                                          \
    MFMA_CLUSTER(1);                                                            \
  } while (0)

  STAGE_KT(0, 0);
  STAGE_KT(1, 1);
#pragma unroll 1
  for (int it = 0; it < NKT - 2; it += 2) {
    KTILE(6, true, it, 0);
    KTILE(6, true, it + 1, 1);
  }
  KTILE(6, false, NKT - 2, 0);
  KTILE(0, false, NKT - 1, 1);

  const int lo = lane & 15;
  if constexpr (EPI == 1) {
    const int head = bn * 2 + wn;
    if (head < 32) {
      f16* dst = (head < 16) ? Qf : Kf;
      const int h15 = head & 15;
      const int h16l = lane >> 4;
      const int ahi = h16l >> 1, kkl = h16l & 1;
      #pragma unroll
      for (int j = 0; j < 4; ++j) {
        const int grow = bm * 256 + wm * 64 + j * 16 + lo;
        const int bb = grow >> 11, ll = grow & 2047;
        float msc = 1.0f;
        if (head < 16) msc = mask[bb * 2048 + ll] ? 0.18033688011112042f : 0.0f;
        f16* base = dst + (size_t)(bb * 16 + h15) * 64 * 2048;
        union { f16x8 v; fp16v2 hh[4]; } u0, u1;
        #pragma unroll
        for (int i = 0; i < 2; ++i) {
          float y0[4], y1[4];
          #pragma unroll
          for (int r = 0; r < 4; ++r) {
            const float2 cs = cst[(size_t)(i * 16 + 4 * h16l + r) * 2048 + ll];
            const float xl = acc[i][j][r], xh = acc[i + 2][j][r];
            y0[r] = (xl * cs.x - xh * cs.y) * msc;
            y1[r] = (xh * cs.x + xl * cs.y) * msc;
          }
          u0.hh[i * 2 + 0] = __builtin_amdgcn_cvt_pkrtz(y0[0], y0[1]);
          u0.hh[i * 2 + 1] = __builtin_amdgcn_cvt_pkrtz(y0[2], y0[3]);
          u1.hh[i * 2 + 0] = __builtin_amdgcn_cvt_pkrtz(y1[0], y1[1]);
          u1.hh[i * 2 + 1] = __builtin_amdgcn_cvt_pkrtz(y1[2], y1[3]);
        }
        const int t = ll >> 5, q5 = ll & 31;
        f16* p = base + (size_t)t * 2048 + (ahi * 32 + q5) * 8;
        *(f16x8*)(p + (kkl + 0) * 512) = u0.v;
        *(f16x8*)(p + (kkl + 2) * 512) = u1.v;
      }
    } else {
      const int hv = head - 32;
      #pragma unroll
      for (int i = 0; i < 4; ++i) {
        #pragma unroll
        for (int j = 0; j < 4; ++j) {
          #pragma unroll
          for (int r = 0; r < 4; ++r) {
            const int gm = bm * 256 + wm * 64 + i * 16 + (lane >> 4) * 4 + r;
            const int bb = gm >> 11, ll = gm & 2047;
            const int dd = j * 16 + lo;
            const int k = ll & 31;
            const int i32 = (k & ~12) | ((k & 4) << 1) | ((k & 8) >> 1);  // swap bits 2,3
            const int cc = i32 >> 4, hih = (i32 >> 3) & 1, jj = i32 & 7;
            const int blk = dd >> 5, qq = dd & 31;
            Vf[((size_t)(bb * 16 + hv) * 64 + (ll >> 5)) * 2048 +
               (cc * 2 + blk) * 512 + hih * 256 + qq * 8 + jj] = (f16)acc[i][j][r];
          }
        }
      }
    }
  } else {
    #pragma unroll
    for (int i = 0; i < 4; ++i) {
      #pragma unroll
      for (int j = 0; j < 4; ++j) {
        #pragma unroll
        for (int r = 0; r < 4; ++r) {
          const int gm = bm * 256 + wm * 64 + i * 16 + (lane >> 4) * 4 + r;
          const int gn = bn * 128 + wn * 64 + j * 16 + lo;
          const float mv = mask[gm] ? 1.0f : 0.0f;
          Cout[(size_t)gm * 1024 + gn] = acc[i][j][r] * mv;
        }
      }
    }
  }
#undef KTILE
#undef MFMA_CLUSTER
#undef STAGE_KT
}

// ---------------- flash attention: R11 + sched_barrier-pinned 2-deep K/V prefetch ----------
// VGPR starvation fix: sched_barrier(0) after each LOADKV pins the loads at their written
// position (compiler can no longer sink them to just-before-use), so tile t+1's 8 loads
// issue a full body (~250cy) ahead of first use and stay live in registers.
#define LOADKV(kd, vd, kp, vp)                       \
  do {                                               \
    _Pragma("unroll")                                \
    for (int _i = 0; _i < 4; ++_i) {                 \
      kd[_i] = *(const f16x8*)&(kp)[_i * 512];       \
      vd[_i] = *(const f16x8*)&(vp)[_i * 512];       \
    }                                                \
  } while (0)

#define ATTN_BODY64(kr, vr)                                                      \
  do {                                                                           \
    f32x16 sa = {}, sb = {};                                                     \
    __builtin_amdgcn_s_setprio(1);                                               \
    _Pragma("unroll")                                                            \
    for (int _k = 0; _k < 4; ++_k)                                               \
      sa = __builtin_amdgcn_mfma_f32_32x32x16_f16(kr[_k], qfa[_k], sa, 0, 0, 0); \
    _Pragma("unroll")                                                            \
    for (int _k = 0; _k < 4; ++_k)                                               \
      sb = __builtin_amdgcn_mfma_f32_32x32x16_f16(kr[_k], qfb[_k], sb, 0, 0, 0); \
    __builtin_amdgcn_s_setprio(0);                                               \
    union PU { fp16v2 h[4]; f16x8 v; } pa0, pa1, pb0, pb1;                       \
    _Pragma("unroll")                                                            \
    for (int _i = 0; _i < 4; ++_i) {                                             \
      pa0.h[_i] = __builtin_amdgcn_cvt_pkrtz(EXP2F(sa[2 * _i]), EXP2F(sa[2 * _i + 1]));       \
      pa1.h[_i] = __builtin_amdgcn_cvt_pkrtz(EXP2F(sa[8 + 2 * _i]), EXP2F(sa[8 + 2 * _i + 1])); \
      la = FDOT2(pa0.h[_i], kOne, la);                                           \
      la = FDOT2(pa1.h[_i], kOne, la);                                           \
    }                                                                            \
    _Pragma("unroll")                                                            \
    for (int _i = 0; _i < 4; ++_i) {                                             \
      pb0.h[_i] = __builtin_amdgcn_cvt_pkrtz(EXP2F(sb[2 * _i]), EXP2F(sb[2 * _i + 1]));       \
      pb1.h[_i] = __builtin_amdgcn_cvt_pkrtz(EXP2F(sb[8 + 2 * _i]), EXP2F(sb[8 + 2 * _i + 1])); \
      lb = FDOT2(pb0.h[_i], kOne, lb);                                           \
      lb = FDOT2(pb1.h[_i], kOne, lb);                                           \
    }                                                                            \
    __builtin_amdgcn_s_setprio(1);                                               \
    oa0 = __builtin_amdgcn_mfma_f32_32x32x16_f16(vr[0], pa0.v, oa0, 0, 0, 0);    \
    oa1 = __builtin_amdgcn_mfma_f32_32x32x16_f16(vr[1], pa0.v, oa1, 0, 0, 0);    \
    ob0 = __builtin_amdgcn_mfma_f32_32x32x16_f16(vr[0], pb0.v, ob0, 0, 0, 0);    \
    ob1 = __builtin_amdgcn_mfma_f32_32x32x16_f16(vr[1], pb0.v, ob1, 0, 0, 0);    \
    oa0 = __builtin_amdgcn_mfma_f32_32x32x16_f16(vr[2], pa1.v, oa0, 0, 0, 0);    \
    oa1 = __builtin_amdgcn_mfma_f32_32x32x16_f16(vr[3], pa1.v, oa1, 0, 0, 0);    \
    ob0 = __builtin_amdgcn_mfma_f32_32x32x16_f16(vr[2], pb1.v, ob0, 0, 0, 0);    \
    ob1 = __builtin_amdgcn_mfma_f32_32x32x16_f16(vr[3], pb1.v, ob1, 0, 0, 0);    \
    __builtin_amdgcn_s_setprio(0);                                               \
  } while (0)

__global__ __launch_bounds__(512, 2) void attn_kernel(const f16* __restrict__ Qf,
                                                      const f16* __restrict__ Kf,
                                                      const f16* __restrict__ Vf,
                                                      f16* __restrict__ Ow) {
  const int bid = (blockIdx.x & 7) * 64 + (blockIdx.x >> 3);  // XCD-chunked swizzle (512=8*64)
  const int bh = bid >> 3;
  const int qt = bid & 7;
  const int lane = threadIdx.x & 63;
  const int wid = threadIdx.x >> 6;
  const int qw = wid & 3;
  const int kvh = wid >> 2;
  const int hi = lane >> 5;
  const int q = lane & 31;

  __shared__ float o_lds[8][32][65];
  __shared__ float l_lds[8][32];

  const f16* Qb = Qf + (size_t)bh * 64 * 2048;
  const f16* Kb = Kf + (size_t)bh * 64 * 2048;
  const f16* Vb = Vf + (size_t)bh * 64 * 2048;

  const int ta = qt * 8 + qw * 2;
  f16x8 qfa[4], qfb[4];
  {
    const f16* pa = Qb + (size_t)ta * 2048 + lane * 8;
    const f16* pb = pa + 2048;
    #pragma unroll
    for (int kk = 0; kk < 4; ++kk) {
      qfa[kk] = *(const f16x8*)&pa[kk * 512];
      qfb[kk] = *(const f16x8*)&pb[kk * 512];
    }
  }

  f32x16 oa0 = {}, oa1 = {}, ob0 = {}, ob1 = {};
  float la = 0.0f, lb = 0.0f;
  const fp16v2 kOne = {(__fp16)1.0f, (__fp16)1.0f};

  const f16* kptr = Kb + (size_t)(kvh * 32) * 2048 + lane * 8;
  const f16* vptr = Vb + (size_t)(kvh * 32) * 2048 + lane * 8;
  f16x8 ka[4], va[4], kn[4], vn[4];
  LOADKV(ka, va, kptr, vptr);
  __builtin_amdgcn_sched_barrier(0);
#pragma unroll 1
  for (int t = 0; t < 32; t += 2) {
    LOADKV(kn, vn, kptr + 2048, vptr + 2048);   // prefetch t+1
    __builtin_amdgcn_sched_barrier(0);          // pin: do not sink below body
    ATTN_BODY64(ka, va);                        // compute t
    if (t + 2 < 32) {
      LOADKV(ka, va, kptr + 4096, vptr + 4096); // prefetch t+2
    }
    __builtin_amdgcn_sched_barrier(0);          // pin
    ATTN_BODY64(kn, vn);                        // compute t+1
    kptr += 4096; vptr += 4096;
  }

  float lha = la + __shfl_xor(la, 32, 64);
  float lhb = lb + __shfl_xor(lb, 32, 64);

  if (kvh == 1) {
    #pragma unroll
    for (int blk = 0; blk < 2; ++blk)
      #pragma unroll
      for (int g = 0; g < 4; ++g)
        #pragma unroll
        for (int j = 0; j < 4; ++j) {
          const int d = blk * 32 + g * 8 + 4 * hi + j;
          o_lds[qw * 2 + 0][q][d] = blk ? oa1[g * 4 + j] : oa0[g * 4 + j];
          o_lds[qw * 2 + 1][q][d] = blk ? ob1[g * 4 + j] : ob0[g * 4 + j];
        }
    if (hi == 0) { l_lds[qw * 2 + 0][q] = lha; l_lds[qw * 2 + 1][q] = lhb; }
  }
  __syncthreads();
  if (kvh == 0) {
    const float inva = 1.0f / (lha + l_lds[qw * 2 + 0][q]);
    const float invb = 1.0f / (lhb + l_lds[qw * 2 + 1][q]);
    const int b = bh >> 4, h = bh & 15;
    const int qra = qt * 256 + qw * 64 + q;
    f16* orowa = Ow + ((size_t)(b * 2048 + qra)) * 1024 + h * 64;
    f16* orowb = orowa + 32 * 1024;
    #pragma unroll
    for (int blk = 0; blk < 2; ++blk) {
      #pragma unroll
      for (int g = 0; g < 4; ++g) {
        f16x4 sta, stb;
        #pragma unroll
        for (int j = 0; j < 4; ++j) {
          const int d = blk * 32 + g * 8 + 4 * hi + j;
          sta[j] = (f16)(((blk ? oa1[g * 4 + j] : oa0[g * 4 + j]) + o_lds[qw * 2 + 0][q][d]) * inva);
          stb[j] = (f16)(((blk ? ob1[g * 4 + j] : ob0[g * 4 + j]) + o_lds[qw * 2 + 1][q][d]) * invb);
        }
        *(f16x4*)&orowa[blk * 32 + g * 8 + 4 * hi] = sta;
        *(f16x4*)&orowb[blk * 32 + g * 8 + 4 * hi] = stb;
      }
    }
  }
}

// ---------------- launch ----------------
extern "C" void kernel_launch(void* const* d_in, const int* in_sizes, int n_in,
                              void* d_out, int out_size, void* d_ws, size_t ws_size,
                              hipStream_t stream) {
  const float* hidden = (const float*)d_in[0];
  const float* cosb   = (const float*)d_in[1];
  const float* sinb   = (const float*)d_in[2];
  const int*   mask   = (const int*)d_in[3];
  const float* wqkv   = (const float*)d_in[4];
  const float* wo     = (const float*)d_in[5];
  float* out = (float*)d_out;
  char* ws = (char*)d_ws;

  f16* h16    = (f16*)(ws + 0);           // 16 MB (reused as Ow after GEMM1)
  f16* wqkv16 = (f16*)(ws + 16777216);    // 6 MB
  f16* wo16   = (f16*)(ws + 23068672);    // 2 MB
  f16* Qfb    = (f16*)(ws + 25165824);    // 16 MB fragment blocks
  f16* Kfb    = (f16*)(ws + 41943040);    // 16 MB
  f16* Vfb    = (f16*)(ws + 58720256);    // 16 MB
  float2* cst = (float2*)(ws + 75497472); // 512 KB transposed cos/sin
  f16* Ow     = h16;

  cvt_all<<<12544, 256, 0, stream>>>((const float4*)hidden, (f16x4*)h16,
                                     (const float4*)wqkv, (f16x4*)wqkv16,
                                     (const float4*)wo, (f16x4*)wo16,
                                     cosb, sinb, cst);

  gemm_bt2<1, 3072, 1024><<<768, 512, 0, stream>>>(h16, wqkv16, Qfb, Kfb, Vfb,
                                                   nullptr, mask, cst);

  attn_kernel<<<512, 512, 0, stream>>>(Qfb, Kfb, Vfb, Ow);

  gemm_bt2<2, 1024, 1024><<<256, 512, 0, stream>>>(Ow, wo16, nullptr, nullptr, nullptr,
                                                   out, mask, nullptr);
}